// Round 12
// baseline (71.609 us; speedup 1.0000x reference)
//
#include <hip/hip_runtime.h>
#include <stdint.h>

// ---------------------------------------------------------------------------
// Fast math helpers.
// ---------------------------------------------------------------------------
__device__ __forceinline__ float fast_exp(float x) {
  return __builtin_amdgcn_exp2f(x * 1.4426950408889634f);
}
__device__ __forceinline__ float fast_rcp(float x) {
  return __builtin_amdgcn_rcpf(x);
}
__device__ __forceinline__ float fast_cos(float x) {
  // v_cos takes revolutions; v_fract does the range reduction.
  return __builtin_amdgcn_cosf(__builtin_amdgcn_fractf(x * 0.15915494309189535f));
}
__device__ __forceinline__ float fast_sigmoid(float x) {
  return fast_rcp(1.0f + fast_exp(-x));
}
__device__ __forceinline__ float fast_tanh(float x) {
  return 1.0f - 2.0f * fast_rcp(1.0f + fast_exp(2.0f * x));
}
// sigmoid on [-1,1]: 0.5 + x/4 - x^3/48 + x^5/480 - 17x^7/80640 (err ~2e-5)
__device__ __forceinline__ float sigmoid_poly(float x) {
  float x2 = x * x;
  float p = fmaf(fmaf(fmaf(-2.1085373e-4f, x2, 2.0833334e-3f), x2,
                      -2.0833334e-2f), x2, 0.25f);
  return fmaf(x, p, 0.5f);
}
// tanh Pade(5,4): err <1e-6 @|x|<=1, <1.3e-4 @|x|<=2.5 (cell state bound ~2.1)
__device__ __forceinline__ float tanh_pade(float x) {
  float x2 = x * x;
  float num = x * fmaf(x2 + 105.f, x2, 945.f);
  float den = fmaf(fmaf(15.f, x2, 420.f), x2, 945.f);
  return num * fast_rcp(den);
}

// Cross-lane XOR exchange within each 4-lane quad via DPP quad_perm
// (update_dpp, tied-old operand — verified correct R7; ~4cy VALU).
template <int CTRL>
__device__ __forceinline__ float dppf(float v) {
  return __int_as_float(__builtin_amdgcn_update_dpp(
      0, __float_as_int(v), CTRL, 0xf, 0xf, true));
}
#define QP_XOR1 0xB1  // [1,0,3,2]
#define QP_XOR2 0x4E  // [2,3,0,1]
#define QP_XOR3 0x1B  // [3,2,1,0]

// Direct global->LDS DMA, 16B per lane. NO VGPR destination => no live-range
// hazard (R11's asm-load failure mode is structurally impossible here).
// Dest: wave-uniform base + lane*16 (linear). Source: per-lane address.
__device__ __forceinline__ void gload_lds16(const float* gp, const float* lp) {
  __builtin_amdgcn_global_load_lds(
      reinterpret_cast<const uint32_t __attribute__((address_space(1)))*>(
          reinterpret_cast<uintptr_t>(gp)),
      reinterpret_cast<uint32_t __attribute__((address_space(3)))*>(
          reinterpret_cast<uintptr_t>(lp)),
      16, 0, 0);
}

// ---------------------------------------------------------------------------
// Kernel 1: precompute x-part of gate activations.
//   Z layout: [t][b][gate][4]  (j=0,1,2 = wire0/wire1/wire3 angle, pad)
//   value = x[t,b,:] . W_g[row_j, :D] + fold  (linear rows {0,1,3}; row 2 is
//   dead: RZ on |0> is a global phase). fold = bias+theta for rows 0,3.
// Structure (evidence-driven, unchanged from R10 — warm ~26-36us, near the
// 21us one-pass HBM floor):
//  - 1-wave workgroups (R6), padded [64][36] LDS tile: 0 bank conflicts.
//  - loads feed ds_write immediately (R4: hoisted prefetch spilled to scratch).
//  - scalar FMA (R9: pk-FMA regressed; latency-bound not issue-bound).
// ---------------------------------------------------------------------------
__global__ __launch_bounds__(64) void qlstm_gemm(
    const float* __restrict__ x,
    const float* __restrict__ Wf, const float* __restrict__ bf,
    const float* __restrict__ Wi, const float* __restrict__ bi,
    const float* __restrict__ Wu, const float* __restrict__ bu,
    const float* __restrict__ Wo, const float* __restrict__ bo,
    const float* __restrict__ thf, const float* __restrict__ thi,
    const float* __restrict__ thu, const float* __restrict__ tho,
    float* __restrict__ Z, long long rows, int B, int D)
{
  __shared__ float tile[64][36];
  const long long base = (long long)blockIdx.x * 64;
  const int tid = threadIdx.x;  // 0..63
  const long long r = base + tid;
  const bool valid = r < rows;
  const int ldw = D + 4;
  const float* Ws[4] = {Wf, Wi, Wu, Wo};
  const float* bs[4] = {bf, bi, bu, bo};
  const float* ts[4] = {thf, thi, thu, tho};

  float acc[12];
#pragma unroll
  for (int g = 0; g < 4; ++g) {
    acc[g * 3 + 0] = bs[g][0] + ts[g][0];  // theta0 folded
    acc[g * 3 + 1] = bs[g][1];
    acc[g * 3 + 2] = bs[g][3] + ts[g][3];  // theta3 folded
  }

  const int nkc = D >> 5;  // D multiple of 32 (D=128)
  for (int kc = 0; kc < nkc; ++kc) {
    // stage 64 rows x 32 cols, coalesced (8 rows of 128B per instruction)
#pragma unroll
    for (int i = 0; i < 8; ++i) {
      int f = i * 64 + tid;
      int row = f >> 3, col = (f & 7) * 4;
      long long gr = base + row;
      if (gr < rows) {
        float4 v = *(const float4*)(x + gr * (long long)D + kc * 32 + col);
        *(float4*)&tile[row][col] = v;
      }
    }
    __syncthreads();  // 1-wave workgroup: near-free
    if (valid) {
#pragma unroll
      for (int k = 0; k < 32; k += 4) {
        float4 xv = *(float4*)&tile[tid][k];
#pragma unroll
        for (int g = 0; g < 4; ++g) {
#pragma unroll
          for (int jj = 0; jj < 3; ++jj) {
            int row2 = (jj == 2) ? 3 : jj;
            const float* wp = Ws[g] + row2 * ldw + kc * 32 + k;  // uniform -> s_load
            acc[g * 3 + jj] += xv.x * wp[0] + xv.y * wp[1] + xv.z * wp[2] + xv.w * wp[3];
          }
        }
      }
    }
    __syncthreads();
  }

  if (valid) {
    float* zp = Z + r * 16;  // [t][b][gate][4] layout, 64B per row
#pragma unroll
    for (int g = 0; g < 4; ++g) {
      *(float4*)(zp + g * 4) =
          make_float4(acc[g * 3 + 0], acc[g * 3 + 1], acc[g * 3 + 2], 0.f);
    }
  }
}

// ---------------------------------------------------------------------------
// Kernel 2: scan with 4 lanes per batch element (lane q = gate q; after the
// 4x4 quad transpose lane q = component q). Cross-lane via DPP quad_perm.
//
// Z delivery via bulk global->LDS DMA, double-buffered 16-step chunks
// (2 x 16KB). Per-step the lane reads its 16B slot from LDS: addresses are
// chunk-known (no dependence on h), so the compiler pipelines ds_reads with
// counted lgkmcnt — bypassing its global-load scheduling (R7-R10: register
// prefetch depth/count all NEUTRAL; R11's asm-load retest was unsound).
// Counted vmcnt: prologue vmcnt(16); steady vmcnt(32) (= 16 stores(k) +
// 16 DMA(k+2) newer than DMA(k+1), in-order retirement); tail vmcnt(16).
// ---------------------------------------------------------------------------
__global__ __launch_bounds__(64) void qlstm_scan4(
    const float* __restrict__ Z,
    const float* __restrict__ Wf, const float* __restrict__ Wi,
    const float* __restrict__ Wu, const float* __restrict__ Wo,
    const float* __restrict__ thf, const float* __restrict__ thi,
    const float* __restrict__ thu, const float* __restrict__ tho,
    float* __restrict__ out, int T, int B, int D)
{
  __shared__ float lds[2][16][256];  // [buf][t_local][lane*4] = 2 x 16KB
  const int tid = threadIdx.x;
  const int gid = blockIdx.x * 64 + tid;
  const int b = gid >> 2, q = gid & 3;
  if (b >= B) return;

  const float* Wg = (q == 0) ? Wf : (q == 1) ? Wi : (q == 2) ? Wu : Wo;
  const float* th = (q == 0) ? thf : (q == 1) ? thi : (q == 2) ? thu : tho;
  const int ldw = D + 4;
  const float ct1 = fast_cos(th[1]);  // cos(theta1) of this lane's gate
  const float m2c = fast_cos(th[2]);  // cos(theta2) of this lane's gate

  // wh[jj][d] pairs with h from lane q^d (component q^d): XOR-permuted load.
  float wh[3][4];
#pragma unroll
  for (int jj = 0; jj < 3; ++jj) {
    int row = (jj == 2) ? 3 : jj;
#pragma unroll
    for (int d = 0; d < 4; ++d)
      wh[jj][d] = Wg[row * ldw + D + (q ^ d)];
  }
  const bool e0 = ((q & 1) == 0);
  const bool e1 = ((q & 2) == 0);

  float h = 0.f, c = 0.f;  // this lane holds component q of h and c

  const float* Zlane = Z + (size_t)gid * 4;  // lane's float4 slot in a t-slab
  const size_t tstr = (size_t)16 * B;        // floats per time step
  const size_t pstr = (size_t)4 * B;         // out floats per time step
  float* hx  = out + (size_t)T * B * 4;
  float* cxp = hx + (size_t)B * 4;

  auto step = [&](float4 zv, int t) {
    float z0 = zv.x, z1 = zv.y, z2 = zv.z;
    // gather all 4 h components (h from lane q^d)
    float h1 = dppf<QP_XOR1>(h);
    float h2 = dppf<QP_XOR2>(h);
    float h3 = dppf<QP_XOR3>(h);
    float a0 = fmaf(wh[0][0], h, fmaf(wh[0][1], h1, fmaf(wh[0][2], h2, fmaf(wh[0][3], h3, z0))));
    float a1 = fmaf(wh[1][0], h, fmaf(wh[1][1], h1, fmaf(wh[1][2], h2, fmaf(wh[1][3], h3, z1))));
    float a2 = fmaf(wh[2][0], h, fmaf(wh[2][1], h1, fmaf(wh[2][2], h2, fmaf(wh[2][3], h3, z2))));
    // this lane's gate: wire measurements
    float m0 = fast_cos(a0);
    float m1 = ct1 * fast_cos(a1);
    float m3 = fast_cos(a2);
    float m01 = m0 * m1, m23 = m2c * m3;
    float g0 = m1 * m23;        // <Z0> = m1 m2 m3
    float g1 = m01;             // <Z1> = m0 m1
    float g2 = m01 * m2c;       // <Z2> = m0 m1 m2
    float g3 = m01 * m23;       // <Z3> = m0 m1 m2 m3
    // 4x4 quad transpose (two XOR stages); after: w_r = gate r's component q.
    float x0 = dppf<QP_XOR1>(g0);
    float x1 = dppf<QP_XOR1>(g1);
    float x2 = dppf<QP_XOR1>(g2);
    float x3 = dppf<QP_XOR1>(g3);
    float s0 = e0 ? g0 : x1;
    float s1 = e0 ? x0 : g1;
    float s2 = e0 ? g2 : x3;
    float s3 = e0 ? x2 : g3;
    float y0 = dppf<QP_XOR2>(s0);
    float y1 = dppf<QP_XOR2>(s1);
    float y2 = dppf<QP_XOR2>(s2);
    float y3 = dppf<QP_XOR2>(s3);
    float wf_ = e1 ? s0 : y2;
    float wi_ = e1 ? s1 : y3;
    float wu_ = e1 ? y0 : s2;
    float wo_ = e1 ? y1 : s3;
    // gates (|input| <= 1: products of cosines)
    float fg = sigmoid_poly(wf_);
    float ig = sigmoid_poly(wi_);
    float ug = tanh_pade(wu_);
    float og = sigmoid_poly(wo_);
    c = fmaf(fg, c, ig * ug);
    h = og * tanh_pade(c);
    out[(size_t)t * pstr + gid] = h;
  };

  // stage 16 t-slabs (one chunk) into lds[buf]: dest linear (lane*16B),
  // source per-lane; one DMA instruction per t.
  auto issue_chunk = [&](int tbase, int buf) {
#pragma unroll
    for (int tl = 0; tl < 16; ++tl) {
      gload_lds16(Zlane + (size_t)(tbase + tl) * tstr, &lds[buf][tl][0]);
    }
  };

  if (T >= 32 && (T & 15) == 0) {
    const int nch = T >> 4;
    issue_chunk(0, 0);
    issue_chunk(16, 1);
    // DMA(chunk0) done: exactly 16 ops (DMA chunk1) are newer.
    asm volatile("s_waitcnt vmcnt(16)" ::: "memory");
    __builtin_amdgcn_sched_barrier(0);
    int cur = 0;
    for (int k = 0; k < nch; ++k) {
      const int tb = k << 4;
#pragma unroll
      for (int tl = 0; tl < 16; ++tl) {
        float4 zv = *(const float4*)&lds[cur][tl][tid * 4];
        step(zv, tb + tl);
      }
      if (k + 2 < nch) issue_chunk((k + 2) << 4, cur);
      cur ^= 1;
      if (k + 1 < nch) {
        if (k + 2 < nch) {
          // newer than DMA(k+1): stores(k)=16 + DMA(k+2)=16
          asm volatile("s_waitcnt vmcnt(32)" ::: "memory");
        } else {
          // last chunk: newer than DMA(k+1): stores(k)=16 only
          asm volatile("s_waitcnt vmcnt(16)" ::: "memory");
        }
        __builtin_amdgcn_sched_barrier(0);
      }
    }
  } else {
    for (int t = 0; t < T; ++t) {
      float4 zv = *(const float4*)(Zlane + (size_t)t * tstr);
      step(zv, t);
    }
  }

  hx[gid]  = h;
  cxp[gid] = c;
}

// ---------------------------------------------------------------------------
// Fallback (only if workspace can't hold Z): fused, slow but correct.
// ---------------------------------------------------------------------------
struct GK {
  float wh[4][3][4];
  float ct1[4];
  float m2c[4];
};

__device__ __forceinline__ void load_gk(GK& K,
    const float* Wf, const float* Wi, const float* Wu, const float* Wo,
    const float* thf, const float* thi, const float* thu, const float* tho,
    int D)
{
  const float* Ws[4] = {Wf, Wi, Wu, Wo};
  const float* ts[4] = {thf, thi, thu, tho};
  const int ldw = D + 4;
#pragma unroll
  for (int g = 0; g < 4; ++g) {
#pragma unroll
    for (int jj = 0; jj < 3; ++jj) {
      int row = (jj == 2) ? 3 : jj;
#pragma unroll
      for (int qq = 0; qq < 4; ++qq)
        K.wh[g][jj][qq] = Ws[g][row * ldw + D + qq];
    }
    K.ct1[g] = fast_cos(ts[g][1]);
    K.m2c[g] = fast_cos(ts[g][2]);
  }
}

__device__ __forceinline__ void qlstm_step_sc(const float a[12], const GK& K,
                                              float h[4], float c[4])
{
  float gv[4][4];
#pragma unroll
  for (int g = 0; g < 4; ++g) {
    float m0 = fast_cos(a[g * 3 + 0]);
    float m1 = K.ct1[g] * fast_cos(a[g * 3 + 1]);
    float m3 = fast_cos(a[g * 3 + 2]);
    float m01 = m0 * m1;
    float m23 = K.m2c[g] * m3;
    gv[g][0] = m1 * m23;
    gv[g][1] = m01;
    gv[g][2] = m01 * K.m2c[g];
    gv[g][3] = m01 * m23;
  }
#pragma unroll
  for (int qq = 0; qq < 4; ++qq) {
    float fg = fast_sigmoid(gv[0][qq]);
    float ig = fast_sigmoid(gv[1][qq]);
    float ug = fast_tanh(gv[2][qq]);
    float og = fast_sigmoid(gv[3][qq]);
    c[qq] = fg * c[qq] + ig * ug;
    h[qq] = og * fast_tanh(c[qq]);
  }
}

__global__ __launch_bounds__(256) void qlstm_fused(
    const float* __restrict__ x,
    const float* __restrict__ Wf, const float* __restrict__ bf,
    const float* __restrict__ Wi, const float* __restrict__ bi,
    const float* __restrict__ Wu, const float* __restrict__ bu,
    const float* __restrict__ Wo, const float* __restrict__ bo,
    const float* __restrict__ thf, const float* __restrict__ thi,
    const float* __restrict__ thu, const float* __restrict__ tho,
    float* __restrict__ out, int T, int B, int D)
{
  int b = blockIdx.x * 256 + threadIdx.x;
  if (b >= B) return;
  GK K;
  load_gk(K, Wf, Wi, Wu, Wo, thf, thi, thu, tho, D);
  const float* Ws[4] = {Wf, Wi, Wu, Wo};
  const float* bs[4] = {bf, bi, bu, bo};
  const float* ts[4] = {thf, thi, thu, tho};
  const int ldw = D + 4;

  float base[12];
#pragma unroll
  for (int g = 0; g < 4; ++g) {
    base[g * 3 + 0] = bs[g][0] + ts[g][0];
    base[g * 3 + 1] = bs[g][1];
    base[g * 3 + 2] = bs[g][3] + ts[g][3];
  }

  float h[4] = {0.f, 0.f, 0.f, 0.f};
  float c[4] = {0.f, 0.f, 0.f, 0.f};
  float* hx  = out + (size_t)T * B * 4;
  float* cxp = hx + (size_t)B * 4;

  for (int t = 0; t < T; ++t) {
    float a[12];
#pragma unroll
    for (int j = 0; j < 12; ++j) a[j] = base[j];
    const float* xp = x + ((size_t)t * B + b) * D;
    for (int k = 0; k < D; k += 4) {
      float4 xv = *(const float4*)(xp + k);
#pragma unroll
      for (int g = 0; g < 4; ++g) {
        const float* W = Ws[g];
#pragma unroll
        for (int jj = 0; jj < 3; ++jj) {
          int row = (jj == 2) ? 3 : jj;
          const float* wp = W + row * ldw + k;
          a[g * 3 + jj] += xv.x * wp[0] + xv.y * wp[1] + xv.z * wp[2] + xv.w * wp[3];
        }
      }
    }
#pragma unroll
    for (int g = 0; g < 4; ++g) {
#pragma unroll
      for (int jj = 0; jj < 3; ++jj) {
        a[g * 3 + jj] += K.wh[g][jj][0] * h[0] + K.wh[g][jj][1] * h[1]
                       + K.wh[g][jj][2] * h[2] + K.wh[g][jj][3] * h[3];
      }
    }
    qlstm_step_sc(a, K, h, c);
    *(float4*)(out + ((size_t)t * B + b) * 4) = make_float4(h[0], h[1], h[2], h[3]);
  }
  *(float4*)(hx + (size_t)b * 4)  = make_float4(h[0], h[1], h[2], h[3]);
  *(float4*)(cxp + (size_t)b * 4) = make_float4(c[0], c[1], c[2], c[3]);
}

// ---------------------------------------------------------------------------
extern "C" void kernel_launch(void* const* d_in, const int* in_sizes, int n_in,
                              void* d_out, int out_size, void* d_ws, size_t ws_size,
                              hipStream_t stream)
{
  const float* x   = (const float*)d_in[0];
  const float* Wf  = (const float*)d_in[1];
  const float* bf  = (const float*)d_in[2];
  const float* Wi  = (const float*)d_in[3];
  const float* bi  = (const float*)d_in[4];
  const float* Wu  = (const float*)d_in[5];
  const float* bu  = (const float*)d_in[6];
  const float* Wo  = (const float*)d_in[7];
  const float* bo  = (const float*)d_in[8];
  const float* thf = (const float*)d_in[9];
  const float* thi = (const float*)d_in[10];
  const float* thu = (const float*)d_in[11];
  const float* tho = (const float*)d_in[12];

  int DH = in_sizes[1] / 4;                 // D + H (H = 4)
  int D  = DH - 4;                          // 128
  long long TB = (long long)in_sizes[0] / D;          // T*B
  int B = (int)(((long long)out_size - 4 * TB) / 8);  // out = 4*T*B + 8*B
  int T = (int)(TB / B);

  size_t zbytes = (size_t)TB * 16 * sizeof(float);
  if (ws_size >= zbytes && (D & 31) == 0 && (B & 15) == 0) {
    float* Z = (float*)d_ws;
    int gblocks = (int)((TB + 63) / 64);
    qlstm_gemm<<<gblocks, 64, 0, stream>>>(x, Wf, bf, Wi, bi, Wu, bu, Wo, bo,
                                           thf, thi, thu, tho, Z, TB, B, D);
    int sthreads = B * 4;
    qlstm_scan4<<<(sthreads + 63) / 64, 64, 0, stream>>>(Z, Wf, Wi, Wu, Wo,
                                                         thf, thi, thu, tho,
                                                         (float*)d_out, T, B, D);
  } else {
    qlstm_fused<<<(B + 255) / 256, 256, 0, stream>>>(x, Wf, bf, Wi, bi, Wu, bu, Wo, bo,
                                                     thf, thi, thu, tho,
                                                     (float*)d_out, T, B, D);
  }
}